// Round 1
// baseline (331.302 us; speedup 1.0000x reference)
//
#include <hip/hip_runtime.h>
#include <hip/hip_bf16.h>
#include <stdint.h>

// ---------------------------------------------------------------------------
// FusionNet: seq[t,d] = sum_r w[r]*(imu1[t]@A[r,:,d])*(vid1[t]@Bv[r,:,d]) + fb[d]
//            out[t]   = (relu(seq@W1 + b1) @ W2 + b2) / (anthro0*anthro1)
// Strategy: bf16 MFMA (16x16x32) for the two [*,128]x[128,160] projections
// (95% of FLOPs), constant "ones" row handled as post-MFMA scalar add,
// fusion_weights folded into imu weights, fusion_bias folded into b1.
// ---------------------------------------------------------------------------

#define NTOK   262144      // B*S = 64*4096
#define FDIM   128
#define RANKN  16
#define FUSED  10
#define KPAD   136         // 128 + 8 pad: LDS bank-conflict-free ds_read_b128
#define WTE    (FUSED*RANKN*KPAD)   // 21760 elements per bf16 weight table

typedef unsigned short u16;
typedef __bf16 bf16x8 __attribute__((ext_vector_type(8)));
typedef float  f32x4  __attribute__((ext_vector_type(4)));

static __device__ __forceinline__ u16 f2bf(float f) {
    union { float f; uint32_t u; } c; c.f = f;
    uint32_t u = c.u + 0x7FFFu + ((c.u >> 16) & 1u);   // RNE
    return (u16)(u >> 16);
}

// ---------------------------------------------------------------------------
// Prep: build transposed bf16 weight tables W[d][r][k] (k = feature-1),
// constant rows a0/b0 (the "ones" column), and b1' = b1 + fusion_bias @ W1.
// fusion_weights[r] folded into imu side (weights and a0).
// ---------------------------------------------------------------------------
__global__ void prep_kernel(const float* __restrict__ imf, const float* __restrict__ vif,
                            const float* __restrict__ fw,  const float* __restrict__ fb,
                            const float* __restrict__ W1,  const float* __restrict__ b1,
                            u16* __restrict__ wImu, u16* __restrict__ wVid,
                            float* __restrict__ a0, float* __restrict__ b0,
                            float* __restrict__ b1p) {
    int idx = blockIdx.x * blockDim.x + threadIdx.x;
    if (idx < FUSED * RANKN * FDIM) {           // 20480
        int k = idx & 127;
        int r = (idx >> 7) & 15;
        int d = idx >> 11;
        int src = r * ((FDIM + 1) * FUSED) + (k + 1) * FUSED + d;  // factor[r,0,k+1,d]
        wImu[(d * RANKN + r) * KPAD + k] = f2bf(fw[r] * imf[src]);
        wVid[(d * RANKN + r) * KPAD + k] = f2bf(vif[src]);
    }
    if (idx < RANKN * FUSED) {                  // 160, layout [d][r]
        int r = idx & 15, d = idx >> 4;
        int src = r * ((FDIM + 1) * FUSED) + d; // factor[r,0,0,d]
        a0[idx] = fw[r] * imf[src];
        b0[idx] = vif[src];
    }
    if (idx < FDIM) {                           // fold fusion_bias through W1
        float acc = b1[idx];
        #pragma unroll
        for (int d = 0; d < FUSED; ++d) acc += fb[d] * W1[d * FDIM + idx];
        b1p[idx] = acc;
    }
}

// ---------------------------------------------------------------------------
// Main: 512 threads = 8 waves per block, each wave owns 16 tokens.
// ---------------------------------------------------------------------------
__launch_bounds__(512, 2)
__global__ void fusion_main(const float* __restrict__ imu, const float* __restrict__ vid,
                            const float* __restrict__ anthro,
                            const u16* __restrict__ wImuG, const u16* __restrict__ wVidG,
                            const float* __restrict__ a0g, const float* __restrict__ b0g,
                            const float* __restrict__ W1g, const float* __restrict__ b1pg,
                            const float* __restrict__ W2g, const float* __restrict__ b2g,
                            float* __restrict__ out) {
    extern __shared__ char smem[];
    u16*   sWimu = (u16*)smem;            // [10][16][136] bf16
    u16*   sWvid = sWimu + WTE;
    float* sA0   = (float*)(sWvid + WTE); // [10][16]
    float* sB0   = sA0 + 160;
    float* sW1   = sB0 + 160;             // [10][128] f32
    float* sB1   = sW1 + 1280;            // [128]
    float* sW2   = sB1 + 128;             // [128][2]

    // ---- stage weights to LDS (uint4 copies, coalesced) ----
    {
        const uint4* srcI = (const uint4*)wImuG;
        const uint4* srcV = (const uint4*)wVidG;
        uint4* dstI = (uint4*)sWimu;
        uint4* dstV = (uint4*)sWvid;
        const int n16 = WTE * 2 / 16;     // 2720 per table
        for (int i = threadIdx.x; i < n16; i += blockDim.x) { dstI[i] = srcI[i]; dstV[i] = srcV[i]; }
        for (int i = threadIdx.x; i < 160;  i += blockDim.x) { sA0[i] = a0g[i]; sB0[i] = b0g[i]; }
        for (int i = threadIdx.x; i < 1280; i += blockDim.x) sW1[i] = W1g[i];
        for (int i = threadIdx.x; i < 128;  i += blockDim.x) sB1[i] = b1pg[i];
        for (int i = threadIdx.x; i < 256;  i += blockDim.x) sW2[i] = W2g[i];
    }
    __syncthreads();

    const int lane = threadIdx.x & 63;
    const int quad = lane >> 4;          // MFMA quad (k-group / row-group)
    const int r16  = lane & 15;          // token row (A) / rank col (B,C)
    const int wid  = threadIdx.x >> 6;
    const int t0   = (blockIdx.x * 8 + wid) * 16;

    // ---- A-fragments for 16 tokens, both modalities, 4 k-steps ----
    // lane holds A[m=r16][k=quad*8+j]; 8 consecutive f32 -> 2x float4 loads + cvt
    bf16x8 aI[4], aV[4];
    {
        const float* baseI = imu + (size_t)(t0 + r16) * FDIM + quad * 8;
        const float* baseV = vid + (size_t)(t0 + r16) * FDIM + quad * 8;
        #pragma unroll
        for (int kk = 0; kk < 4; ++kk) {
            f32x4 v0 = *(const f32x4*)(baseI + kk * 32);
            f32x4 v1 = *(const f32x4*)(baseI + kk * 32 + 4);
            f32x4 w0 = *(const f32x4*)(baseV + kk * 32);
            f32x4 w1 = *(const f32x4*)(baseV + kk * 32 + 4);
            bf16x8 a, b;
            #pragma unroll
            for (int j = 0; j < 4; ++j) {
                a[j]     = (__bf16)v0[j];
                a[j + 4] = (__bf16)v1[j];
                b[j]     = (__bf16)w0[j];
                b[j + 4] = (__bf16)w1[j];
            }
            aI[kk] = a;
            aV[kk] = b;
        }
    }

    // ---- per fused-dim d: U,V via MFMA (N=16=rank), rank-reduce butterfly ----
    float seqv[4][FUSED];    // [acc reg -> token quad*4+reg][d]
    #pragma unroll
    for (int d = 0; d < FUSED; ++d) {
        f32x4 accU = {0.f, 0.f, 0.f, 0.f};
        f32x4 accV = {0.f, 0.f, 0.f, 0.f};
        const u16* bi = sWimu + (d * RANKN + r16) * KPAD + quad * 8;
        const u16* bv = sWvid + (d * RANKN + r16) * KPAD + quad * 8;
        #pragma unroll
        for (int kk = 0; kk < 4; ++kk) {
            bf16x8 bU = *(const bf16x8*)(const void*)(bi + kk * 32);
            accU = __builtin_amdgcn_mfma_f32_16x16x32_bf16(aI[kk], bU, accU, 0, 0, 0);
            bf16x8 bV = *(const bf16x8*)(const void*)(bv + kk * 32);
            accV = __builtin_amdgcn_mfma_f32_16x16x32_bf16(aV[kk], bV, accV, 0, 0, 0);
        }
        // add "ones"-row constants, multiply modalities, reduce over rank (16 lanes)
        float a0v = sA0[d * RANKN + r16];
        float b0v = sB0[d * RANKN + r16];
        #pragma unroll
        for (int reg = 0; reg < 4; ++reg) {
            float p = (accU[reg] + a0v) * (accV[reg] + b0v);
            p += __shfl_xor(p, 1, 16);
            p += __shfl_xor(p, 2, 16);
            p += __shfl_xor(p, 4, 16);
            p += __shfl_xor(p, 8, 16);
            seqv[reg][d] = p;            // all 16 lanes of quad hold it
        }
    }

    // ---- MLP: h = relu(seq@W1 + b1'), out = h@W2 + b2; j split by r16 ----
    float o0[4] = {0.f, 0.f, 0.f, 0.f};
    float o1[4] = {0.f, 0.f, 0.f, 0.f};
    #pragma unroll
    for (int g = 0; g < 8; ++g) {
        const int jc = r16 + 16 * g;
        float bb = sB1[jc];
        float h[4] = {bb, bb, bb, bb};
        #pragma unroll
        for (int d = 0; d < FUSED; ++d) {
            float w1v = sW1[d * FDIM + jc];
            #pragma unroll
            for (int reg = 0; reg < 4; ++reg) h[reg] += seqv[reg][d] * w1v;
        }
        float w20 = sW2[jc * 2], w21 = sW2[jc * 2 + 1];
        #pragma unroll
        for (int reg = 0; reg < 4; ++reg) {
            float hr = fmaxf(h[reg], 0.f);
            o0[reg] += hr * w20;
            o1[reg] += hr * w21;
        }
    }
    #pragma unroll
    for (int reg = 0; reg < 4; ++reg) {
        o0[reg] += __shfl_xor(o0[reg], 1, 16);
        o0[reg] += __shfl_xor(o0[reg], 2, 16);
        o0[reg] += __shfl_xor(o0[reg], 4, 16);
        o0[reg] += __shfl_xor(o0[reg], 8, 16);
        o1[reg] += __shfl_xor(o1[reg], 1, 16);
        o1[reg] += __shfl_xor(o1[reg], 2, 16);
        o1[reg] += __shfl_xor(o1[reg], 4, 16);
        o1[reg] += __shfl_xor(o1[reg], 8, 16);
    }

    // ---- epilogue: + b2, / (w*h), store float2 per token ----
    const int bidx = t0 >> 12;                         // S = 4096
    const float invwh = 1.0f / (anthro[2 * bidx] * anthro[2 * bidx + 1]);
    const float b20 = b2g[0], b21 = b2g[1];
    if (r16 == 0) {
        #pragma unroll
        for (int reg = 0; reg < 4; ++reg) {
            const int t = t0 + quad * 4 + reg;
            float2 o = make_float2((o0[reg] + b20) * invwh, (o1[reg] + b21) * invwh);
            *(float2*)(out + 2 * t) = o;
        }
    }
}

// ---------------------------------------------------------------------------
extern "C" void kernel_launch(void* const* d_in, const int* in_sizes, int n_in,
                              void* d_out, int out_size, void* d_ws, size_t ws_size,
                              hipStream_t stream) {
    const float* imu    = (const float*)d_in[0];
    const float* vid    = (const float*)d_in[1];
    const float* anthro = (const float*)d_in[2];
    const float* imf    = (const float*)d_in[3];
    const float* vif    = (const float*)d_in[4];
    const float* fw     = (const float*)d_in[5];
    const float* fb     = (const float*)d_in[6];
    const float* W1     = (const float*)d_in[7];
    const float* b1     = (const float*)d_in[8];
    const float* W2     = (const float*)d_in[9];
    const float* b2     = (const float*)d_in[10];
    float* out = (float*)d_out;

    // workspace layout: [wImu bf16 21760][wVid bf16 21760][a0 160][b0 160][b1p 128]
    u16* wImu = (u16*)d_ws;
    u16* wVid = wImu + WTE;
    float* a0  = (float*)(wVid + WTE);
    float* b0  = a0 + 160;
    float* b1p = b0 + 160;

    prep_kernel<<<80, 256, 0, stream>>>(imf, vif, fw, fb, W1, b1, wImu, wVid, a0, b0, b1p);

    const size_t smem = (size_t)(2 * WTE) * sizeof(u16)
                      + (size_t)(160 + 160 + 1280 + 128 + 256) * sizeof(float); // 94976 B
    // 262144 tokens / (8 waves * 16 tokens) = 2048 blocks
    fusion_main<<<2048, 512, smem, stream>>>(imu, vid, anthro, wImu, wVid,
                                             a0, b0, W1, b1p, W2, b2, out);
}